// Round 1
// baseline (281.128 us; speedup 1.0000x reference)
//
#include <hip/hip_runtime.h>
#include <hip/hip_bf16.h>

// Problem dims (fixed by reference)
#define BATCH 8
#define CH    512
#define NN    4096
#define OUT_C 512

// Tile config
#define BM  256
#define BN  128
#define BK  32
#define NTH 512
#define LDP 40   // padded LDS row length in ushort (80 B, 16B-aligned frag reads)

typedef float  f32x4  __attribute__((ext_vector_type(4)));
typedef __bf16 bf16x8 __attribute__((ext_vector_type(8)));

__device__ __forceinline__ unsigned int pack_bf2(float a, float b) {
    // RNE f32->bf16, pack two into one u32 (a = low half, b = high half)
    unsigned int ua = __float_as_uint(a);
    ua += 0x7FFFu + ((ua >> 16) & 1u);
    unsigned int ub = __float_as_uint(b);
    ub += 0x7FFFu + ((ub >> 16) & 1u);
    return (ua >> 16) | (ub & 0xFFFF0000u);
}

__device__ __forceinline__ float sample_one(const float* __restrict__ xr,
                                            const float* __restrict__ orow,
                                            int gn, float gnf) {
    float o  = orow[gn];
    float pp = gnf + o;           // bit-exact vs reference (f32 add)
    float fl = floorf(pp);
    float fr = pp - fl;
    int   li = (int)fl;
    float v0 = (li >= 0  && li < NN)     ? xr[li]     : 0.f;
    float v1 = (li >= -1 && li < NN - 1) ? xr[li + 1] : 0.f;
    return v0 * (1.f - fr) + v1 * fr;
}

__global__ __launch_bounds__(NTH) void atm_fused(
    const float* __restrict__ x, const float* __restrict__ offs,
    const float* __restrict__ w, const float* __restrict__ bias,
    const int* __restrict__ amask, float* __restrict__ out)
{
    __shared__ unsigned short Alds[BM][LDP];  // W tile, bf16, [m][k]
    __shared__ unsigned short Blds[BN][LDP];  // sampled tile, bf16, [n][k]

    const int tid = threadIdx.x;
    const int n0  = blockIdx.x * BN;
    const int m0  = blockIdx.y * BM;
    const int b   = blockIdx.z;

    const float* xb = x    + (size_t)b * CH * NN;
    const float* ob = offs + (size_t)b * CH * NN;

    // ---- B-staging coords (sampling): thread owns one n, 4 c-pairs/K-step
    const int   sn  = tid & 127;
    const int   sc0 = (tid >> 7) * 2;      // 0,2,4,6
    const int   gn  = n0 + sn;
    const int   mv  = amask[b * NN + gn];  // whole column dead if 0
    const float gnf = (float)gn;

    // ---- A-staging coords: thread owns half a W row (16 f32) per K-step
    const int ar = tid >> 1;               // 0..255
    const int ah = (tid & 1) * 16;         // k offset 0 / 16
    const float* wrow = w + (size_t)(m0 + ar) * CH + ah;

    // ---- wave/output mapping
    const int l   = tid & 63;
    const int wid = tid >> 6;              // 0..7
    const int wmb = (wid >> 1) * 64;       // wave m offset (0,64,128,192)
    const int wnb = (wid & 1) * 64;        // wave n offset (0,64)
    const int fr_ = l & 15;
    const int fkB = (l >> 4) * 16;         // frag k byte offset: (l>>4)*8 bf16

    f32x4 acc[4][4];
    #pragma unroll
    for (int i = 0; i < 4; ++i)
        #pragma unroll
        for (int j = 0; j < 4; ++j)
            acc[i][j] = (f32x4){0.f, 0.f, 0.f, 0.f};

    for (int k0 = 0; k0 < CH; k0 += BK) {
        __syncthreads();   // previous tile's frag reads done before overwrite

        // ---- stage A: W f32 -> bf16
        #pragma unroll
        for (int i = 0; i < 4; ++i) {
            f32x4 v = *(const f32x4*)(wrow + k0 + i * 4);
            *(unsigned int*)&Alds[ar][ah + i * 4]     = pack_bf2(v[0], v[1]);
            *(unsigned int*)&Alds[ar][ah + i * 4 + 2] = pack_bf2(v[2], v[3]);
        }

        // ---- stage B: deformable bilinear sample -> bf16
        #pragma unroll
        for (int p = 0; p < 4; ++p) {
            const int cl = sc0 + p * 8;    // even, covers 0..30
            float s0 = 0.f, s1 = 0.f;
            if (mv) {
                const int c = k0 + cl;
                s0 = sample_one(xb + (size_t)c * NN,       ob + (size_t)c * NN,       gn, gnf);
                s1 = sample_one(xb + (size_t)(c + 1) * NN, ob + (size_t)(c + 1) * NN, gn, gnf);
            }
            *(unsigned int*)&Blds[sn][cl] = pack_bf2(s0, s1);
        }

        __syncthreads();

        // ---- fragments + MFMA
        bf16x8 af[4], bfr[4];
        #pragma unroll
        for (int mf = 0; mf < 4; ++mf)
            af[mf] = *(const bf16x8*)((const char*)&Alds[0][0] +
                       (size_t)(wmb + mf * 16 + fr_) * (LDP * 2) + fkB);
        #pragma unroll
        for (int nf = 0; nf < 4; ++nf)
            bfr[nf] = *(const bf16x8*)((const char*)&Blds[0][0] +
                       (size_t)(wnb + nf * 16 + fr_) * (LDP * 2) + fkB);
        #pragma unroll
        for (int mf = 0; mf < 4; ++mf)
            #pragma unroll
            for (int nf = 0; nf < 4; ++nf)
                acc[mf][nf] = __builtin_amdgcn_mfma_f32_16x16x32_bf16(
                                  af[mf], bfr[nf], acc[mf][nf], 0, 0, 0);
    }

    // ---- epilogue: acc + bias -> out  (D: row=(l>>4)*4+r, col=l&15)
    const int col = l & 15;
    const int rg  = (l >> 4) * 4;
    float* outb = out + (size_t)b * OUT_C * NN;
    #pragma unroll
    for (int mf = 0; mf < 4; ++mf) {
        const int mbase = m0 + wmb + mf * 16 + rg;
        #pragma unroll
        for (int r = 0; r < 4; ++r) {
            const float bv = bias[mbase + r];
            float* orow = outb + (size_t)(mbase + r) * NN + n0 + wnb + col;
            #pragma unroll
            for (int nf = 0; nf < 4; ++nf)
                orow[nf * 16] = acc[mf][nf][r] + bv;
        }
    }
}

extern "C" void kernel_launch(void* const* d_in, const int* in_sizes, int n_in,
                              void* d_out, int out_size, void* d_ws, size_t ws_size,
                              hipStream_t stream) {
    const float* x    = (const float*)d_in[0];
    const float* offs = (const float*)d_in[1];
    const float* w    = (const float*)d_in[2];
    const float* bias = (const float*)d_in[3];
    const int*   am   = (const int*)d_in[4];
    float* out        = (float*)d_out;

    dim3 grid(NN / BN, OUT_C / BM, BATCH);
    atm_fused<<<grid, NTH, 0, stream>>>(x, offs, w, bias, am, out);
}

// Round 3
// 210.996 us; speedup vs baseline: 1.3324x; 1.3324x over previous
//
#include <hip/hip_runtime.h>
#include <hip/hip_bf16.h>

// Problem dims (fixed by reference)
#define BATCH 8
#define CH    512
#define NN    4096
#define OUT_C 512

typedef float        f32x4  __attribute__((ext_vector_type(4)));
typedef __bf16       bf16x8 __attribute__((ext_vector_type(8)));
typedef unsigned int u32;
typedef unsigned int u32x4  __attribute__((ext_vector_type(4)));

__device__ __forceinline__ u32 pack_bf2(float a, float b) {
    u32 ua = __float_as_uint(a);
    ua += 0x7FFFu + ((ua >> 16) & 1u);
    u32 ub = __float_as_uint(b);
    ub += 0x7FFFu + ((ub >> 16) & 1u);
    return (ua >> 16) | (ub & 0xFFFF0000u);
}

__device__ __forceinline__ float sample_one(const float* __restrict__ xr,
                                            const float* __restrict__ orow,
                                            int gn, float gnf) {
    float o  = orow[gn];
    float pp = gnf + o;           // bit-exact vs reference (f32 add)
    float fl = floorf(pp);
    float fr = pp - fl;
    int   li = (int)fl;
    float v0 = (li >= 0  && li < NN)     ? xr[li]     : 0.f;
    float v1 = (li >= -1 && li < NN - 1) ? xr[li + 1] : 0.f;
    return v0 * (1.f - fr) + v1 * fr;
}

// ============================ kernel: W f32 -> bf16 =========================
__global__ __launch_bounds__(256) void wconv(const float* __restrict__ w,
                                             unsigned short* __restrict__ wb) {
    const int t = blockIdx.x * 256 + threadIdx.x;   // 8 elems per thread
    const float* src = w + (size_t)t * 8;
    f32x4 a = *(const f32x4*)src;
    f32x4 c = *(const f32x4*)(src + 4);
    u32x4 o;
    o.x = pack_bf2(a[0], a[1]); o.y = pack_bf2(a[2], a[3]);
    o.z = pack_bf2(c[0], c[1]); o.w = pack_bf2(c[2], c[3]);
    *(u32x4*)(wb + (size_t)t * 8) = o;
}

// ============ kernel: deformable sample + mask -> S^T[b][n][c] bf16 =========
__global__ __launch_bounds__(256) void sampler(
    const float* __restrict__ x, const float* __restrict__ offs,
    const int* __restrict__ amask, unsigned short* __restrict__ st)
{
    __shared__ u32 T[64][33];   // [n][c-pair], pitch 33 -> write banks = (sn+cp)%32

    const int tid = threadIdx.x;
    const int n0  = blockIdx.x * 64;
    const int c0  = blockIdx.y * 64;
    const int b   = blockIdx.z;
    const int sn  = tid & 63;
    const int cg  = tid >> 6;             // 0..3
    const int gn  = n0 + sn;
    const int mv  = amask[b * NN + gn];
    const float gnf = (float)gn;
    const float* xb = x    + (size_t)b * CH * NN;
    const float* ob = offs + (size_t)b * CH * NN;

    #pragma unroll
    for (int i = 0; i < 8; ++i) {
        const int cp = cg * 8 + i;        // c-pair index within tile (0..31)
        const int c  = c0 + cp * 2;
        float s0 = 0.f, s1 = 0.f;
        if (mv) {
            s0 = sample_one(xb + (size_t)c * NN,       ob + (size_t)c * NN,       gn, gnf);
            s1 = sample_one(xb + (size_t)(c + 1) * NN, ob + (size_t)(c + 1) * NN, gn, gnf);
        }
        T[sn][cp] = pack_bf2(s0, s1);
    }
    __syncthreads();

    // write transposed tile: row n has 32 u32 (64 bf16 channels)
    u32* stb = (u32*)st + (size_t)b * NN * (CH / 2);
    #pragma unroll
    for (int j = 0; j < 2; ++j) {
        const int r   = (tid >> 3) + j * 32;
        const int seg = tid & 7;
        u32x4 v = { T[r][seg * 4 + 0], T[r][seg * 4 + 1],
                    T[r][seg * 4 + 2], T[r][seg * 4 + 3] };
        *(u32x4*)(stb + (size_t)(n0 + r) * (CH / 2) + (c0 >> 1) + seg * 4) = v;
    }
}

// ====================== kernel: batched GEMM (m97 structure) ================
#define BM 128
#define BN 128
#define BK 32

__global__ __launch_bounds__(256) void gemm(
    const unsigned short* __restrict__ wb,   // [OUT_C][CH] bf16, k-contig
    const unsigned short* __restrict__ st,   // [B][NN][CH] bf16, k-contig
    const float* __restrict__ bias, float* __restrict__ out)
{
    __shared__ unsigned short Al[BM * BK];   // [m][k], 64B rows
    __shared__ unsigned short Bl[BN * BK];   // [n][k]

    const int tid = threadIdx.x;
    const int l   = tid & 63;
    const int wid = tid >> 6;                // 0..3
    const int n0  = blockIdx.x * BN;
    const int m0  = blockIdx.y * BM;
    const int b   = blockIdx.z;
    const unsigned short* sb = st + (size_t)b * NN * CH;

    const int arow = l >> 2;                 // row within 16-row chunk
    const int aseg = (l & 3) * 8;            // k offset (shorts)

    const int wm  = (wid >> 1) * 64;
    const int wn  = (wid & 1) * 64;
    const int fr_ = l & 15;
    const int fk  = (l >> 4) * 8;            // frag k offset (shorts)

    f32x4 acc[4][4];
    #pragma unroll
    for (int i = 0; i < 4; ++i)
        #pragma unroll
        for (int j = 0; j < 4; ++j)
            acc[i][j] = (f32x4){0.f, 0.f, 0.f, 0.f};

    for (int k0 = 0; k0 < CH; k0 += BK) {
        __syncthreads();   // all waves done with previous tile
        #pragma unroll
        for (int i = 0; i < 2; ++i) {
            const int ci = i * 4 + wid;      // 1KB chunk = 16 rows
            const unsigned short* ga = wb + (size_t)(m0 + ci * 16 + arow) * CH + k0 + aseg;
            __builtin_amdgcn_global_load_lds(
                (const __attribute__((address_space(1))) u32*)ga,
                (__attribute__((address_space(3))) u32*)(Al + ci * 512), 16, 0, 0);
            const unsigned short* gb = sb + (size_t)(n0 + ci * 16 + arow) * CH + k0 + aseg;
            __builtin_amdgcn_global_load_lds(
                (const __attribute__((address_space(1))) u32*)gb,
                (__attribute__((address_space(3))) u32*)(Bl + ci * 512), 16, 0, 0);
        }
        __syncthreads();   // staged tile visible (vmcnt drained at barrier)

        bf16x8 af[4], bfr[4];
        #pragma unroll
        for (int mf = 0; mf < 4; ++mf)
            af[mf] = *(const bf16x8*)(Al + (wm + mf * 16 + fr_) * BK + fk);
        #pragma unroll
        for (int nf = 0; nf < 4; ++nf)
            bfr[nf] = *(const bf16x8*)(Bl + (wn + nf * 16 + fr_) * BK + fk);
        #pragma unroll
        for (int mf = 0; mf < 4; ++mf)
            #pragma unroll
            for (int nf = 0; nf < 4; ++nf)
                acc[mf][nf] = __builtin_amdgcn_mfma_f32_16x16x32_bf16(
                                  af[mf], bfr[nf], acc[mf][nf], 0, 0, 0);
    }

    // epilogue: D row=(l>>4)*4+r, col=l&15
    const int col = l & 15;
    const int rg  = (l >> 4) * 4;
    float* outb = out + (size_t)b * OUT_C * NN;
    #pragma unroll
    for (int mf = 0; mf < 4; ++mf) {
        const int mbase = m0 + wm + mf * 16 + rg;
        #pragma unroll
        for (int r = 0; r < 4; ++r) {
            const float bv = bias[mbase + r];
            float* orow = outb + (size_t)(mbase + r) * NN + n0 + wn + col;
            #pragma unroll
            for (int nf = 0; nf < 4; ++nf)
                orow[nf * 16] = acc[mf][nf][r] + bv;
        }
    }
}

// ===================== fallback: round-1 fused kernel =======================
#define FBM  256
#define FBN  128
#define FNTH 512
#define FLDP 40

__global__ __launch_bounds__(FNTH) void atm_fused(
    const float* __restrict__ x, const float* __restrict__ offs,
    const float* __restrict__ w, const float* __restrict__ bias,
    const int* __restrict__ amask, float* __restrict__ out)
{
    __shared__ unsigned short Alds[FBM][FLDP];
    __shared__ unsigned short Blds[FBN][FLDP];

    const int tid = threadIdx.x;
    const int n0  = blockIdx.x * FBN;
    const int m0  = blockIdx.y * FBM;
    const int b   = blockIdx.z;

    const float* xb = x    + (size_t)b * CH * NN;
    const float* ob = offs + (size_t)b * CH * NN;

    const int   sn  = tid & 127;
    const int   sc0 = (tid >> 7) * 2;
    const int   gn  = n0 + sn;
    const int   mv  = amask[b * NN + gn];
    const float gnf = (float)gn;

    const int ar = tid >> 1;
    const int ah = (tid & 1) * 16;
    const float* wrow = w + (size_t)(m0 + ar) * CH + ah;

    const int l   = tid & 63;
    const int wid = tid >> 6;
    const int wmb = (wid >> 1) * 64;
    const int wnb = (wid & 1) * 64;
    const int fr_ = l & 15;
    const int fkB = (l >> 4) * 16;

    f32x4 acc[4][4];
    #pragma unroll
    for (int i = 0; i < 4; ++i)
        #pragma unroll
        for (int j = 0; j < 4; ++j)
            acc[i][j] = (f32x4){0.f, 0.f, 0.f, 0.f};

    for (int k0 = 0; k0 < CH; k0 += 32) {
        __syncthreads();
        #pragma unroll
        for (int i = 0; i < 4; ++i) {
            f32x4 v = *(const f32x4*)(wrow + k0 + i * 4);
            *(u32*)&Alds[ar][ah + i * 4]     = pack_bf2(v[0], v[1]);
            *(u32*)&Alds[ar][ah + i * 4 + 2] = pack_bf2(v[2], v[3]);
        }
        #pragma unroll
        for (int p = 0; p < 4; ++p) {
            const int cl = sc0 + p * 8;
            float s0 = 0.f, s1 = 0.f;
            if (mv) {
                const int c = k0 + cl;
                s0 = sample_one(xb + (size_t)c * NN,       ob + (size_t)c * NN,       gn, gnf);
                s1 = sample_one(xb + (size_t)(c + 1) * NN, ob + (size_t)(c + 1) * NN, gn, gnf);
            }
            *(u32*)&Blds[sn][cl] = pack_bf2(s0, s1);
        }
        __syncthreads();

        bf16x8 af[4], bfr[4];
        #pragma unroll
        for (int mf = 0; mf < 4; ++mf)
            af[mf] = *(const bf16x8*)((const char*)&Alds[0][0] +
                       (size_t)(wmb + mf * 16 + fr_) * (FLDP * 2) + fkB);
        #pragma unroll
        for (int nf = 0; nf < 4; ++nf)
            bfr[nf] = *(const bf16x8*)((const char*)&Blds[0][0] +
                       (size_t)(wnb + nf * 16 + fr_) * (FLDP * 2) + fkB);
        #pragma unroll
        for (int mf = 0; mf < 4; ++mf)
            #pragma unroll
            for (int nf = 0; nf < 4; ++nf)
                acc[mf][nf] = __builtin_amdgcn_mfma_f32_16x16x32_bf16(
                                  af[mf], bfr[nf], acc[mf][nf], 0, 0, 0);
    }

    const int col = l & 15;
    const int rg  = (l >> 4) * 4;
    float* outb = out + (size_t)b * OUT_C * NN;
    #pragma unroll
    for (int mf = 0; mf < 4; ++mf) {
        const int mbase = m0 + wmb + mf * 16 + rg;
        #pragma unroll
        for (int r = 0; r < 4; ++r) {
            const float bv = bias[mbase + r];
            float* orow = outb + (size_t)(mbase + r) * NN + n0 + wnb + col;
            #pragma unroll
            for (int nf = 0; nf < 4; ++nf)
                orow[nf * 16] = acc[mf][nf][r] + bv;
        }
    }
}

// ================================ launch ====================================
extern "C" void kernel_launch(void* const* d_in, const int* in_sizes, int n_in,
                              void* d_out, int out_size, void* d_ws, size_t ws_size,
                              hipStream_t stream) {
    const float* x    = (const float*)d_in[0];
    const float* offs = (const float*)d_in[1];
    const float* w    = (const float*)d_in[2];
    const float* bias = (const float*)d_in[3];
    const int*   am   = (const int*)d_in[4];
    float* out        = (float*)d_out;

    const size_t wb_bytes = (size_t)OUT_C * CH * 2;                 // 512 KB
    const size_t st_bytes = (size_t)BATCH * NN * CH * 2;            // 32 MB
    if (ws_size >= wb_bytes + st_bytes) {
        unsigned short* wb = (unsigned short*)d_ws;
        unsigned short* st = (unsigned short*)((char*)d_ws + wb_bytes);

        wconv<<<dim3(OUT_C * CH / 2048), 256, 0, stream>>>(w, wb);
        sampler<<<dim3(NN / 64, CH / 64, BATCH), 256, 0, stream>>>(x, offs, am, st);
        gemm<<<dim3(NN / BN, OUT_C / BM, BATCH), 256, 0, stream>>>(wb, st, bias, out);
    } else {
        dim3 grid(NN / FBN, OUT_C / FBM, BATCH);
        atm_fused<<<grid, FNTH, 0, stream>>>(x, offs, w, bias, am, out);
    }
}

// Round 4
// 203.202 us; speedup vs baseline: 1.3835x; 1.0384x over previous
//
#include <hip/hip_runtime.h>
#include <hip/hip_bf16.h>

// Problem dims (fixed by reference)
#define BATCH 8
#define CH    512
#define NN    4096
#define OUT_C 512

typedef float        f32x4  __attribute__((ext_vector_type(4)));
typedef __bf16       bf16x8 __attribute__((ext_vector_type(8)));
typedef unsigned int u32;
typedef unsigned int u32x4  __attribute__((ext_vector_type(4)));

__device__ __forceinline__ u32 pack_bf2(float a, float b) {
    u32 ua = __float_as_uint(a);
    ua += 0x7FFFu + ((ua >> 16) & 1u);
    u32 ub = __float_as_uint(b);
    ub += 0x7FFFu + ((ub >> 16) & 1u);
    return (ua >> 16) | (ub & 0xFFFF0000u);
}

// ============================ kernel: W f32 -> bf16 =========================
__global__ __launch_bounds__(256) void wconv(const float* __restrict__ w,
                                             unsigned short* __restrict__ wb) {
    const int t = blockIdx.x * 256 + threadIdx.x;   // 8 elems per thread
    const float* src = w + (size_t)t * 8;
    f32x4 a = *(const f32x4*)src;
    f32x4 c = *(const f32x4*)(src + 4);
    u32x4 o;
    o.x = pack_bf2(a[0], a[1]); o.y = pack_bf2(a[2], a[3]);
    o.z = pack_bf2(c[0], c[1]); o.w = pack_bf2(c[2], c[3]);
    *(u32x4*)(wb + (size_t)t * 8) = o;
}

// ============ kernel: deformable sample + mask -> S^T[b][n][c] bf16 =========
// ILP-restructured: all 16 offset loads issued, then all 32 clamped x-gathers,
// then combine. Validity by cndmask, not branches. (Round-3: VGPR=12, serial
// chains, 1.8 TB/s. Target: ~48 outstanding loads/thread.)
__global__ __launch_bounds__(256) void sampler(
    const float* __restrict__ x, const float* __restrict__ offs,
    const int* __restrict__ amask, unsigned short* __restrict__ st)
{
    __shared__ u32 T[64][33];   // [n][c-pair], pitch 33 -> conflict-free both phases

    const int tid = threadIdx.x;
    const int n0  = blockIdx.x * 64;
    const int c0  = blockIdx.y * 64;
    const int b   = blockIdx.z;
    const int sn  = tid & 63;
    const int cg  = tid >> 6;             // 0..3 -> channels c0+cg*16 .. +15
    const int gn  = n0 + sn;
    const int mv  = amask[b * NN + gn];
    const float gnf = (float)gn;

    const float* ob = offs + (size_t)b * CH * NN + (size_t)(c0 + cg * 16) * NN + gn;
    const float* xc = x    + (size_t)b * CH * NN + (size_t)(c0 + cg * 16) * NN;

    float s[16];
    #pragma unroll
    for (int i = 0; i < 16; ++i) s[i] = 0.f;

    if (mv) {
        // phase 1: all offset loads (independent, coalesced across lanes)
        float ov[16];
        #pragma unroll
        for (int i = 0; i < 16; ++i) ov[i] = ob[(size_t)i * NN];

        // phase 2: positions (f32 add/floor bit-exact vs reference)
        float fr[16]; int li[16];
        #pragma unroll
        for (int i = 0; i < 16; ++i) {
            float pp = gnf + ov[i];
            float fl = floorf(pp);
            fr[i] = pp - fl;
            li[i] = (int)fl;
        }

        // phase 3: all x gathers, clamped addresses (no branches)
        float v0[16], v1[16];
        #pragma unroll
        for (int i = 0; i < 16; ++i) {
            const float* xr = xc + (size_t)i * NN;
            int ci0 = min(max(li[i], 0), NN - 1);
            int ci1 = min(max(li[i] + 1, 0), NN - 1);
            v0[i] = xr[ci0];
            v1[i] = xr[ci1];
        }

        // phase 4: validity + lerp
        #pragma unroll
        for (int i = 0; i < 16; ++i) {
            float a = (li[i] >= 0  && li[i] < NN)     ? v0[i] : 0.f;
            float c = (li[i] >= -1 && li[i] < NN - 1) ? v1[i] : 0.f;
            s[i] = a * (1.f - fr[i]) + c * fr[i];
        }
    }

    #pragma unroll
    for (int i = 0; i < 8; ++i)
        T[sn][cg * 8 + i] = pack_bf2(s[2 * i], s[2 * i + 1]);

    __syncthreads();

    // write transposed tile: row n has 32 u32 (64 bf16 channels)
    u32* stb = (u32*)st + (size_t)b * NN * (CH / 2);
    #pragma unroll
    for (int j = 0; j < 2; ++j) {
        const int r   = (tid >> 3) + j * 32;
        const int seg = tid & 7;
        u32x4 v = { T[r][seg * 4 + 0], T[r][seg * 4 + 1],
                    T[r][seg * 4 + 2], T[r][seg * 4 + 3] };
        *(u32x4*)(stb + (size_t)(n0 + r) * (CH / 2) + (c0 >> 1) + seg * 4) = v;
    }
}

// ====================== kernel: batched GEMM (m97 structure) ================
#define BM 128
#define BN 128
#define BK 32

__global__ __launch_bounds__(256) void gemm(
    const unsigned short* __restrict__ wb,   // [OUT_C][CH] bf16, k-contig
    const unsigned short* __restrict__ st,   // [B][NN][CH] bf16, k-contig
    const float* __restrict__ bias, float* __restrict__ out)
{
    __shared__ unsigned short Al[BM * BK];   // [m][k], 64B rows
    __shared__ unsigned short Bl[BN * BK];   // [n][k]

    const int tid = threadIdx.x;
    const int l   = tid & 63;
    const int wid = tid >> 6;                // 0..3
    const int n0  = blockIdx.x * BN;
    const int m0  = blockIdx.y * BM;
    const int b   = blockIdx.z;
    const unsigned short* sb = st + (size_t)b * NN * CH;

    const int arow = l >> 2;                 // row within 16-row chunk
    const int aseg = (l & 3) * 8;            // k offset (shorts)

    const int wm  = (wid >> 1) * 64;
    const int wn  = (wid & 1) * 64;
    const int fr_ = l & 15;
    const int fk  = (l >> 4) * 8;            // frag k offset (shorts)

    f32x4 acc[4][4];
    #pragma unroll
    for (int i = 0; i < 4; ++i)
        #pragma unroll
        for (int j = 0; j < 4; ++j)
            acc[i][j] = (f32x4){0.f, 0.f, 0.f, 0.f};

    for (int k0 = 0; k0 < CH; k0 += BK) {
        __syncthreads();   // all waves done with previous tile
        #pragma unroll
        for (int i = 0; i < 2; ++i) {
            const int ci = i * 4 + wid;      // 1KB chunk = 16 rows
            const unsigned short* ga = wb + (size_t)(m0 + ci * 16 + arow) * CH + k0 + aseg;
            __builtin_amdgcn_global_load_lds(
                (const __attribute__((address_space(1))) u32*)ga,
                (__attribute__((address_space(3))) u32*)(Al + ci * 512), 16, 0, 0);
            const unsigned short* gb = sb + (size_t)(n0 + ci * 16 + arow) * CH + k0 + aseg;
            __builtin_amdgcn_global_load_lds(
                (const __attribute__((address_space(1))) u32*)gb,
                (__attribute__((address_space(3))) u32*)(Bl + ci * 512), 16, 0, 0);
        }
        __syncthreads();   // staged tile visible (vmcnt drained at barrier)

        bf16x8 af[4], bfr[4];
        #pragma unroll
        for (int mf = 0; mf < 4; ++mf)
            af[mf] = *(const bf16x8*)(Al + (wm + mf * 16 + fr_) * BK + fk);
        #pragma unroll
        for (int nf = 0; nf < 4; ++nf)
            bfr[nf] = *(const bf16x8*)(Bl + (wn + nf * 16 + fr_) * BK + fk);
        #pragma unroll
        for (int mf = 0; mf < 4; ++mf)
            #pragma unroll
            for (int nf = 0; nf < 4; ++nf)
                acc[mf][nf] = __builtin_amdgcn_mfma_f32_16x16x32_bf16(
                                  af[mf], bfr[nf], acc[mf][nf], 0, 0, 0);
    }

    // epilogue: D row=(l>>4)*4+r, col=l&15
    const int col = l & 15;
    const int rg  = (l >> 4) * 4;
    float* outb = out + (size_t)b * OUT_C * NN;
    #pragma unroll
    for (int mf = 0; mf < 4; ++mf) {
        const int mbase = m0 + wm + mf * 16 + rg;
        #pragma unroll
        for (int r = 0; r < 4; ++r) {
            const float bv = bias[mbase + r];
            float* orow = outb + (size_t)(mbase + r) * NN + n0 + wn + col;
            #pragma unroll
            for (int nf = 0; nf < 4; ++nf)
                orow[nf * 16] = acc[mf][nf][r] + bv;
        }
    }
}

// ===================== fallback: round-1 fused kernel =======================
#define FBM  256
#define FBN  128
#define FNTH 512
#define FLDP 40

__device__ __forceinline__ float sample_one(const float* __restrict__ xr,
                                            const float* __restrict__ orow,
                                            int gn, float gnf) {
    float o  = orow[gn];
    float pp = gnf + o;
    float fl = floorf(pp);
    float fr = pp - fl;
    int   li = (int)fl;
    float v0 = (li >= 0  && li < NN)     ? xr[li]     : 0.f;
    float v1 = (li >= -1 && li < NN - 1) ? xr[li + 1] : 0.f;
    return v0 * (1.f - fr) + v1 * fr;
}

__global__ __launch_bounds__(FNTH) void atm_fused(
    const float* __restrict__ x, const float* __restrict__ offs,
    const float* __restrict__ w, const float* __restrict__ bias,
    const int* __restrict__ amask, float* __restrict__ out)
{
    __shared__ unsigned short Alds[FBM][FLDP];
    __shared__ unsigned short Blds[FBN][FLDP];

    const int tid = threadIdx.x;
    const int n0  = blockIdx.x * FBN;
    const int m0  = blockIdx.y * FBM;
    const int b   = blockIdx.z;

    const float* xb = x    + (size_t)b * CH * NN;
    const float* ob = offs + (size_t)b * CH * NN;

    const int   sn  = tid & 127;
    const int   sc0 = (tid >> 7) * 2;
    const int   gn  = n0 + sn;
    const int   mv  = amask[b * NN + gn];
    const float gnf = (float)gn;

    const int ar = tid >> 1;
    const int ah = (tid & 1) * 16;
    const float* wrow = w + (size_t)(m0 + ar) * CH + ah;

    const int l   = tid & 63;
    const int wid = tid >> 6;
    const int wmb = (wid >> 1) * 64;
    const int wnb = (wid & 1) * 64;
    const int fr_ = l & 15;
    const int fkB = (l >> 4) * 16;

    f32x4 acc[4][4];
    #pragma unroll
    for (int i = 0; i < 4; ++i)
        #pragma unroll
        for (int j = 0; j < 4; ++j)
            acc[i][j] = (f32x4){0.f, 0.f, 0.f, 0.f};

    for (int k0 = 0; k0 < CH; k0 += 32) {
        __syncthreads();
        #pragma unroll
        for (int i = 0; i < 4; ++i) {
            f32x4 v = *(const f32x4*)(wrow + k0 + i * 4);
            *(u32*)&Alds[ar][ah + i * 4]     = pack_bf2(v[0], v[1]);
            *(u32*)&Alds[ar][ah + i * 4 + 2] = pack_bf2(v[2], v[3]);
        }
        #pragma unroll
        for (int p = 0; p < 4; ++p) {
            const int cl = sc0 + p * 8;
            float s0 = 0.f, s1 = 0.f;
            if (mv) {
                const int c = k0 + cl;
                s0 = sample_one(xb + (size_t)c * NN,       ob + (size_t)c * NN,       gn, gnf);
                s1 = sample_one(xb + (size_t)(c + 1) * NN, ob + (size_t)(c + 1) * NN, gn, gnf);
            }
            *(u32*)&Blds[sn][cl] = pack_bf2(s0, s1);
        }
        __syncthreads();

        bf16x8 af[4], bfr[4];
        #pragma unroll
        for (int mf = 0; mf < 4; ++mf)
            af[mf] = *(const bf16x8*)((const char*)&Alds[0][0] +
                       (size_t)(wmb + mf * 16 + fr_) * (FLDP * 2) + fkB);
        #pragma unroll
        for (int nf = 0; nf < 4; ++nf)
            bfr[nf] = *(const bf16x8*)((const char*)&Blds[0][0] +
                       (size_t)(wnb + nf * 16 + fr_) * (FLDP * 2) + fkB);
        #pragma unroll
        for (int mf = 0; mf < 4; ++mf)
            #pragma unroll
            for (int nf = 0; nf < 4; ++nf)
                acc[mf][nf] = __builtin_amdgcn_mfma_f32_16x16x32_bf16(
                                  af[mf], bfr[nf], acc[mf][nf], 0, 0, 0);
    }

    const int col = l & 15;
    const int rg  = (l >> 4) * 4;
    float* outb = out + (size_t)b * OUT_C * NN;
    #pragma unroll
    for (int mf = 0; mf < 4; ++mf) {
        const int mbase = m0 + wmb + mf * 16 + rg;
        #pragma unroll
        for (int r = 0; r < 4; ++r) {
            const float bv = bias[mbase + r];
            float* orow = outb + (size_t)(mbase + r) * NN + n0 + wnb + col;
            #pragma unroll
            for (int nf = 0; nf < 4; ++nf)
                orow[nf * 16] = acc[mf][nf][r] + bv;
        }
    }
}

// ================================ launch ====================================
extern "C" void kernel_launch(void* const* d_in, const int* in_sizes, int n_in,
                              void* d_out, int out_size, void* d_ws, size_t ws_size,
                              hipStream_t stream) {
    const float* x    = (const float*)d_in[0];
    const float* offs = (const float*)d_in[1];
    const float* w    = (const float*)d_in[2];
    const float* bias = (const float*)d_in[3];
    const int*   am   = (const int*)d_in[4];
    float* out        = (float*)d_out;

    const size_t wb_bytes = (size_t)OUT_C * CH * 2;                 // 512 KB
    const size_t st_bytes = (size_t)BATCH * NN * CH * 2;            // 32 MB
    if (ws_size >= wb_bytes + st_bytes) {
        unsigned short* wb = (unsigned short*)d_ws;
        unsigned short* st = (unsigned short*)((char*)d_ws + wb_bytes);

        wconv<<<dim3(OUT_C * CH / 2048), 256, 0, stream>>>(w, wb);
        sampler<<<dim3(NN / 64, CH / 64, BATCH), 256, 0, stream>>>(x, offs, am, st);
        gemm<<<dim3(NN / BN, OUT_C / BM, BATCH), 256, 0, stream>>>(wb, st, bias, out);
    } else {
        dim3 grid(NN / FBN, OUT_C / FBM, BATCH);
        atm_fused<<<grid, FNTH, 0, stream>>>(x, offs, w, bias, am, out);
    }
}

// Round 5
// 201.895 us; speedup vs baseline: 1.3924x; 1.0065x over previous
//
#include <hip/hip_runtime.h>
#include <hip/hip_bf16.h>

// Problem dims (fixed by reference)
#define BATCH 8
#define CH    512
#define NN    4096
#define OUT_C 512

typedef float        f32x4  __attribute__((ext_vector_type(4)));
typedef __bf16       bf16x8 __attribute__((ext_vector_type(8)));
typedef unsigned int u32;
typedef unsigned int u32x4  __attribute__((ext_vector_type(4)));

__device__ __forceinline__ u32 pack_bf2(float a, float b) {
    u32 ua = __float_as_uint(a);
    ua += 0x7FFFu + ((ua >> 16) & 1u);
    u32 ub = __float_as_uint(b);
    ub += 0x7FFFu + ((ub >> 16) & 1u);
    return (ua >> 16) | (ub & 0xFFFF0000u);
}

// ============================ kernel: W f32 -> bf16 =========================
__global__ __launch_bounds__(256) void wconv(const float* __restrict__ w,
                                             unsigned short* __restrict__ wb) {
    const int t = blockIdx.x * 256 + threadIdx.x;   // 8 elems per thread
    const float* src = w + (size_t)t * 8;
    f32x4 a = *(const f32x4*)src;
    f32x4 c = *(const f32x4*)(src + 4);
    u32x4 o;
    o.x = pack_bf2(a[0], a[1]); o.y = pack_bf2(a[2], a[3]);
    o.z = pack_bf2(c[0], c[1]); o.w = pack_bf2(c[2], c[3]);
    *(u32x4*)(wb + (size_t)t * 8) = o;
}

// ============ kernel: deformable sample + mask -> S^T[b][n][c] bf16 =========
// v3: 512 threads, 8 channels/thread. Round-4 v2 (16 ch/thread) needed ~96
// live f32 but compiler allocated 68 VGPR -> re-serialized loads, 2.1 TB/s,
// 28% occupancy. Halving per-thread state keeps the load clusters intact
// (~40-56 live) AND triples resident waves -> aggregate MLP/CU ~3x.
__global__ __launch_bounds__(512) void sampler(
    const float* __restrict__ x, const float* __restrict__ offs,
    const int* __restrict__ amask, unsigned short* __restrict__ st)
{
    __shared__ u32 T[64][33];   // [n][c-pair], pitch 33

    const int tid = threadIdx.x;
    const int n0  = blockIdx.x * 64;
    const int c0  = blockIdx.y * 64;
    const int b   = blockIdx.z;
    const int sn  = tid & 63;
    const int cg  = tid >> 6;             // 0..7 -> channels c0+cg*8 .. +7
    const int gn  = n0 + sn;
    const int mv  = amask[b * NN + gn];
    const float gnf = (float)gn;

    const float* ob = offs + (size_t)b * CH * NN + (size_t)(c0 + cg * 8) * NN + gn;
    const float* xc = x    + (size_t)b * CH * NN + (size_t)(c0 + cg * 8) * NN;

    float s[8];
    #pragma unroll
    for (int i = 0; i < 8; ++i) s[i] = 0.f;

    if (mv) {
        // phase 1: all offset loads (independent, coalesced across lanes)
        float ov[8];
        #pragma unroll
        for (int i = 0; i < 8; ++i) ov[i] = ob[(size_t)i * NN];

        // phase 2: positions (f32 add/floor bit-exact vs reference)
        float fr[8]; int li[8];
        #pragma unroll
        for (int i = 0; i < 8; ++i) {
            float pp = gnf + ov[i];
            float fl = floorf(pp);
            fr[i] = pp - fl;
            li[i] = (int)fl;
        }

        // phase 3: all x gathers, clamped addresses (no branches)
        float v0[8], v1[8];
        #pragma unroll
        for (int i = 0; i < 8; ++i) {
            const float* xr = xc + (size_t)i * NN;
            int ci0 = min(max(li[i], 0), NN - 1);
            int ci1 = min(max(li[i] + 1, 0), NN - 1);
            v0[i] = xr[ci0];
            v1[i] = xr[ci1];
        }

        // phase 4: validity + lerp
        #pragma unroll
        for (int i = 0; i < 8; ++i) {
            float a = (li[i] >= 0  && li[i] < NN)     ? v0[i] : 0.f;
            float c = (li[i] >= -1 && li[i] < NN - 1) ? v1[i] : 0.f;
            s[i] = a * (1.f - fr[i]) + c * fr[i];
        }
    }

    #pragma unroll
    for (int i = 0; i < 4; ++i)
        T[sn][cg * 4 + i] = pack_bf2(s[2 * i], s[2 * i + 1]);

    __syncthreads();

    // write transposed tile: row n has 32 u32 (64 bf16 channels); 512 threads
    // cover all (r, seg) pairs directly.
    u32* stb = (u32*)st + (size_t)b * NN * (CH / 2);
    const int r   = tid >> 3;
    const int seg = tid & 7;
    u32x4 v = { T[r][seg * 4 + 0], T[r][seg * 4 + 1],
                T[r][seg * 4 + 2], T[r][seg * 4 + 3] };
    *(u32x4*)(stb + (size_t)(n0 + r) * (CH / 2) + (c0 >> 1) + seg * 4) = v;
}

// ====================== kernel: batched GEMM (m97 structure) ================
#define BM 128
#define BN 128
#define BK 32

__global__ __launch_bounds__(256) void gemm(
    const unsigned short* __restrict__ wb,   // [OUT_C][CH] bf16, k-contig
    const unsigned short* __restrict__ st,   // [B][NN][CH] bf16, k-contig
    const float* __restrict__ bias, float* __restrict__ out)
{
    __shared__ unsigned short Al[BM * BK];   // [m][k], 64B rows
    __shared__ unsigned short Bl[BN * BK];   // [n][k]

    const int tid = threadIdx.x;
    const int l   = tid & 63;
    const int wid = tid >> 6;                // 0..3
    const int n0  = blockIdx.x * BN;
    const int m0  = blockIdx.y * BM;
    const int b   = blockIdx.z;
    const unsigned short* sb = st + (size_t)b * NN * CH;

    const int arow = l >> 2;                 // row within 16-row chunk
    const int aseg = (l & 3) * 8;            // k offset (shorts)

    const int wm  = (wid >> 1) * 64;
    const int wn  = (wid & 1) * 64;
    const int fr_ = l & 15;
    const int fk  = (l >> 4) * 8;            // frag k offset (shorts)

    f32x4 acc[4][4];
    #pragma unroll
    for (int i = 0; i < 4; ++i)
        #pragma unroll
        for (int j = 0; j < 4; ++j)
            acc[i][j] = (f32x4){0.f, 0.f, 0.f, 0.f};

    for (int k0 = 0; k0 < CH; k0 += BK) {
        __syncthreads();   // all waves done with previous tile
        #pragma unroll
        for (int i = 0; i < 2; ++i) {
            const int ci = i * 4 + wid;      // 1KB chunk = 16 rows
            const unsigned short* ga = wb + (size_t)(m0 + ci * 16 + arow) * CH + k0 + aseg;
            __builtin_amdgcn_global_load_lds(
                (const __attribute__((address_space(1))) u32*)ga,
                (__attribute__((address_space(3))) u32*)(Al + ci * 512), 16, 0, 0);
            const unsigned short* gb = sb + (size_t)(n0 + ci * 16 + arow) * CH + k0 + aseg;
            __builtin_amdgcn_global_load_lds(
                (const __attribute__((address_space(1))) u32*)gb,
                (__attribute__((address_space(3))) u32*)(Bl + ci * 512), 16, 0, 0);
        }
        __syncthreads();   // staged tile visible (vmcnt drained at barrier)

        bf16x8 af[4], bfr[4];
        #pragma unroll
        for (int mf = 0; mf < 4; ++mf)
            af[mf] = *(const bf16x8*)(Al + (wm + mf * 16 + fr_) * BK + fk);
        #pragma unroll
        for (int nf = 0; nf < 4; ++nf)
            bfr[nf] = *(const bf16x8*)(Bl + (wn + nf * 16 + fr_) * BK + fk);
        #pragma unroll
        for (int mf = 0; mf < 4; ++mf)
            #pragma unroll
            for (int nf = 0; nf < 4; ++nf)
                acc[mf][nf] = __builtin_amdgcn_mfma_f32_16x16x32_bf16(
                                  af[mf], bfr[nf], acc[mf][nf], 0, 0, 0);
    }

    // epilogue: D row=(l>>4)*4+r, col=l&15
    const int col = l & 15;
    const int rg  = (l >> 4) * 4;
    float* outb = out + (size_t)b * OUT_C * NN;
    #pragma unroll
    for (int mf = 0; mf < 4; ++mf) {
        const int mbase = m0 + wm + mf * 16 + rg;
        #pragma unroll
        for (int r = 0; r < 4; ++r) {
            const float bv = bias[mbase + r];
            float* orow = outb + (size_t)(mbase + r) * NN + n0 + wn + col;
            #pragma unroll
            for (int nf = 0; nf < 4; ++nf)
                orow[nf * 16] = acc[mf][nf][r] + bv;
        }
    }
}

// ===================== fallback: round-1 fused kernel =======================
#define FBM  256
#define FBN  128
#define FNTH 512
#define FLDP 40

__device__ __forceinline__ float sample_one(const float* __restrict__ xr,
                                            const float* __restrict__ orow,
                                            int gn, float gnf) {
    float o  = orow[gn];
    float pp = gnf + o;
    float fl = floorf(pp);
    float fr = pp - fl;
    int   li = (int)fl;
    float v0 = (li >= 0  && li < NN)     ? xr[li]     : 0.f;
    float v1 = (li >= -1 && li < NN - 1) ? xr[li + 1] : 0.f;
    return v0 * (1.f - fr) + v1 * fr;
}

__global__ __launch_bounds__(FNTH) void atm_fused(
    const float* __restrict__ x, const float* __restrict__ offs,
    const float* __restrict__ w, const float* __restrict__ bias,
    const int* __restrict__ amask, float* __restrict__ out)
{
    __shared__ unsigned short Alds[FBM][FLDP];
    __shared__ unsigned short Blds[FBN][FLDP];

    const int tid = threadIdx.x;
    const int n0  = blockIdx.x * FBN;
    const int m0  = blockIdx.y * FBM;
    const int b   = blockIdx.z;

    const float* xb = x    + (size_t)b * CH * NN;
    const float* ob = offs + (size_t)b * CH * NN;

    const int   sn  = tid & 127;
    const int   sc0 = (tid >> 7) * 2;
    const int   gn  = n0 + sn;
    const int   mv  = amask[b * NN + gn];
    const float gnf = (float)gn;

    const int ar = tid >> 1;
    const int ah = (tid & 1) * 16;
    const float* wrow = w + (size_t)(m0 + ar) * CH + ah;

    const int l   = tid & 63;
    const int wid = tid >> 6;
    const int wmb = (wid >> 1) * 64;
    const int wnb = (wid & 1) * 64;
    const int fr_ = l & 15;
    const int fkB = (l >> 4) * 16;

    f32x4 acc[4][4];
    #pragma unroll
    for (int i = 0; i < 4; ++i)
        #pragma unroll
        for (int j = 0; j < 4; ++j)
            acc[i][j] = (f32x4){0.f, 0.f, 0.f, 0.f};

    for (int k0 = 0; k0 < CH; k0 += 32) {
        __syncthreads();
        #pragma unroll
        for (int i = 0; i < 4; ++i) {
            f32x4 v = *(const f32x4*)(wrow + k0 + i * 4);
            *(u32*)&Alds[ar][ah + i * 4]     = pack_bf2(v[0], v[1]);
            *(u32*)&Alds[ar][ah + i * 4 + 2] = pack_bf2(v[2], v[3]);
        }
        #pragma unroll
        for (int p = 0; p < 4; ++p) {
            const int cl = sc0 + p * 8;
            float s0 = 0.f, s1 = 0.f;
            if (mv) {
                const int c = k0 + cl;
                s0 = sample_one(xb + (size_t)c * NN,       ob + (size_t)c * NN,       gn, gnf);
                s1 = sample_one(xb + (size_t)(c + 1) * NN, ob + (size_t)(c + 1) * NN, gn, gnf);
            }
            *(u32*)&Blds[sn][cl] = pack_bf2(s0, s1);
        }
        __syncthreads();

        bf16x8 af[4], bfr[4];
        #pragma unroll
        for (int mf = 0; mf < 4; ++mf)
            af[mf] = *(const bf16x8*)((const char*)&Alds[0][0] +
                       (size_t)(wmb + mf * 16 + fr_) * (FLDP * 2) + fkB);
        #pragma unroll
        for (int nf = 0; nf < 4; ++nf)
            bfr[nf] = *(const bf16x8*)((const char*)&Blds[0][0] +
                       (size_t)(wnb + nf * 16 + fr_) * (FLDP * 2) + fkB);
        #pragma unroll
        for (int mf = 0; mf < 4; ++mf)
            #pragma unroll
            for (int nf = 0; nf < 4; ++nf)
                acc[mf][nf] = __builtin_amdgcn_mfma_f32_16x16x32_bf16(
                                  af[mf], bfr[nf], acc[mf][nf], 0, 0, 0);
    }

    const int col = l & 15;
    const int rg  = (l >> 4) * 4;
    float* outb = out + (size_t)b * OUT_C * NN;
    #pragma unroll
    for (int mf = 0; mf < 4; ++mf) {
        const int mbase = m0 + wmb + mf * 16 + rg;
        #pragma unroll
        for (int r = 0; r < 4; ++r) {
            const float bv = bias[mbase + r];
            float* orow = outb + (size_t)(mbase + r) * NN + n0 + wnb + col;
            #pragma unroll
            for (int nf = 0; nf < 4; ++nf)
                orow[nf * 16] = acc[mf][nf][r] + bv;
        }
    }
}

// ================================ launch ====================================
extern "C" void kernel_launch(void* const* d_in, const int* in_sizes, int n_in,
                              void* d_out, int out_size, void* d_ws, size_t ws_size,
                              hipStream_t stream) {
    const float* x    = (const float*)d_in[0];
    const float* offs = (const float*)d_in[1];
    const float* w    = (const float*)d_in[2];
    const float* bias = (const float*)d_in[3];
    const int*   am   = (const int*)d_in[4];
    float* out        = (float*)d_out;

    const size_t wb_bytes = (size_t)OUT_C * CH * 2;                 // 512 KB
    const size_t st_bytes = (size_t)BATCH * NN * CH * 2;            // 32 MB
    if (ws_size >= wb_bytes + st_bytes) {
        unsigned short* wb = (unsigned short*)d_ws;
        unsigned short* st = (unsigned short*)((char*)d_ws + wb_bytes);

        wconv<<<dim3(OUT_C * CH / 2048), 256, 0, stream>>>(w, wb);
        sampler<<<dim3(NN / 64, CH / 64, BATCH), 512, 0, stream>>>(x, offs, am, st);
        gemm<<<dim3(NN / BN, OUT_C / BM, BATCH), 256, 0, stream>>>(wb, st, bias, out);
    } else {
        dim3 grid(NN / FBN, OUT_C / FBM, BATCH);
        atm_fused<<<grid, FNTH, 0, stream>>>(x, offs, w, bias, am, out);
    }
}